// Round 2
// baseline (585.984 us; speedup 1.0000x reference)
//
#include <hip/hip_runtime.h>
#include <stdint.h>

// ---------------- problem constants ----------------
#define B_ROWS   16384
#define D_IN     512
#define N_DIM    1024
#define NREL     16
#define TM       256                   // M/N tile (256x256), expert granularity
#define MAX_TILES 80                   // <= B_ROWS/TM + NREL partial tiles
#define PADDED_ROWS (MAX_TILES * TM)   // 20480

typedef __bf16 bf16x8 __attribute__((ext_vector_type(8)));
typedef float  f32x4  __attribute__((ext_vector_type(4)));

__device__ __forceinline__ uint16_t f2bf(float f) {
  union { float f; uint32_t u; } v; v.f = f;
  return (uint16_t)((v.u + 0x7fffu + ((v.u >> 16) & 1u)) >> 16);   // RNE
}

// async global->LDS 16B copy. LDS dest is wave-uniform base + lane*16.
__device__ __forceinline__ void async_cp16(const uint16_t* g, uint16_t* l) {
  __builtin_amdgcn_global_load_lds(
      (__attribute__((address_space(1))) void*)(g),
      (__attribute__((address_space(3))) void*)(l), 16, 0, 0);
}

// ---------------- setup: histogram relations, build padded permutation ----------------
__global__ void setup_kernel(const int* __restrict__ rel, int* __restrict__ rowidx,
                             int* __restrict__ texp, int* __restrict__ tval) {
  __shared__ int cnt[NREL], segstart[NREL], cursor[NREL];
  const int t = threadIdx.x;
  const int nt_ = blockDim.x;
  if (t < NREL) { cnt[t] = 0; cursor[t] = 0; }
  __syncthreads();
  for (int i = t; i < B_ROWS; i += nt_) atomicAdd(&cnt[rel[i]], 1);
  __syncthreads();
  if (t == 0) {
    int slot = 0, tile = 0;
    for (int r = 0; r < NREL; r++) {
      segstart[r] = slot;
      const int c = cnt[r];
      const int nt = (c + TM - 1) / TM;
      for (int k = 0; k < nt; k++) {
        texp[tile + k] = r;
        const int rem = c - k * TM;
        tval[tile + k] = rem < TM ? rem : TM;
      }
      tile += nt; slot += nt * TM;
    }
    for (; tile < MAX_TILES; tile++) { texp[tile] = 0; tval[tile] = 0; }
  }
  __syncthreads();
  for (int i = t; i < PADDED_ROWS; i += nt_) rowidx[i] = 0;  // padded slots -> row 0 (safe loads)
  __syncthreads();
  for (int i = t; i < B_ROWS; i += nt_) {
    const int r = rel[i];
    const int p = atomicAdd(&cursor[r], 1);
    rowidx[segstart[r] + p] = i;
  }
}

// ---------------- fp32 -> bf16 elementwise (x) ----------------
__global__ void conv_x_kernel(const float* __restrict__ in, uint16_t* __restrict__ out, int n4) {
  const int i = blockIdx.x * blockDim.x + threadIdx.x;
  if (i < n4) {
    const float4 v = ((const float4*)in)[i];
    uint2 o;
    o.x = (uint32_t)f2bf(v.x) | ((uint32_t)f2bf(v.y) << 16);
    o.y = (uint32_t)f2bf(v.z) | ((uint32_t)f2bf(v.w) << 16);
    ((uint2*)out)[i] = o;
  }
}

// ---------------- W[K][N] fp32 -> Wt[N][K] bf16, 64x64 tiles, vectorized ----------------
__global__ __launch_bounds__(256)
void transpose_conv_kernel(const float* __restrict__ W, uint16_t* __restrict__ Wt,
                           int K, int N) {
  __shared__ uint32_t t32[64][33];
  const size_t mat = (size_t)K * N;
  const float*    Wp  = W  + mat * blockIdx.z;
  uint16_t*       Wtp = Wt + mat * blockIdx.z;
  const int n0 = blockIdx.x * 64, k0 = blockIdx.y * 64;
  const int tx = threadIdx.x & 15;     // n-quad
  const int ty = threadIdx.x >> 4;     // 0..15
  #pragma unroll
  for (int rb = 0; rb < 2; rb++) {
    const int kp = rb * 16 + ty;       // k-pair 0..31
    const int k  = k0 + kp * 2;
    const float4 r0 = *(const float4*)&Wp[(size_t)k * N + n0 + tx * 4];
    const float4 r1 = *(const float4*)&Wp[(size_t)(k + 1) * N + n0 + tx * 4];
    t32[tx * 4 + 0][kp] = (uint32_t)f2bf(r0.x) | ((uint32_t)f2bf(r1.x) << 16);
    t32[tx * 4 + 1][kp] = (uint32_t)f2bf(r0.y) | ((uint32_t)f2bf(r1.y) << 16);
    t32[tx * 4 + 2][kp] = (uint32_t)f2bf(r0.z) | ((uint32_t)f2bf(r1.z) << 16);
    t32[tx * 4 + 3][kp] = (uint32_t)f2bf(r0.w) | ((uint32_t)f2bf(r1.w) << 16);
  }
  __syncthreads();
  #pragma unroll
  for (int rb = 0; rb < 4; rb++) {
    const int nl = rb * 16 + ty;
    uint2 v; v.x = t32[nl][2 * tx]; v.y = t32[nl][2 * tx + 1];
    *(uint2*)&Wtp[(size_t)(n0 + nl) * K + k0 + tx * 4] = v;
  }
}

// ---------------- GEMM: 256x256 tile, 8 waves, 8-phase K-half pipeline ----------------
// K-tile = 64 k; each K-tile = 2 K-halves (32 k). 4 LDS halves per K-tile:
//   c0=A[kh0] c1=B[kh0] c2=A[kh1] c3=B[kh1], each 256 rows x 32 k = 16KB.
// 8 half-slots (128KB), slot = h&7. Stage half h at phase h-6 (lead 6).
// Phase q of K-tile T (global phase p=4T+q):
//   q0: read A-frags(kh0)+B j01(kh0); q1: read B j23(kh0);
//   q2: read A(kh1)+B j01(kh1);      q3: read B j23(kh1)
//   each phase: reads; STAGE(p+6); s_barrier; setprio(1); 16 MFMA; setprio(0);
//               [q odd: s_waitcnt vmcnt(8)]; s_barrier
// Residency proof: vmcnt(8) at odd phase p => halves <= p+2 resident; first
// need of half h is phase 4(h>>2)+(h&3<2?0:2) <= (wait phase)+2. Overwrite of
// slot h&7 (old half h-8) at phase h-6 is after old half's last read (<= h-7).
#define MFMA_PAIR(JP)                                                         \
  _Pragma("unroll")                                                           \
  for (int i = 0; i < 8; i++) {                                               \
    acc[i][2*(JP)]   = __builtin_amdgcn_mfma_f32_16x16x32_bf16(af[i], bf[0], acc[i][2*(JP)], 0, 0, 0);   \
    acc[i][2*(JP)+1] = __builtin_amdgcn_mfma_f32_16x16x32_bf16(af[i], bf[1], acc[i][2*(JP)+1], 0, 0, 0); \
  }
#define LDA_FRAGS(SL)                                                         \
  _Pragma("unroll")                                                           \
  for (int i = 0; i < 8; i++) af[i] = *(const bf16x8*)&lds[(SL) + abase + i * 512];
#define LDB_FRAGS(SL, JP)                                                     \
  bf[0] = *(const bf16x8*)&lds[(SL) + bbase + ((JP) * 2 + 0) * 512];          \
  bf[1] = *(const bf16x8*)&lds[(SL) + bbase + ((JP) * 2 + 1) * 512];

template<bool REL, bool RELU, bool F32OUT>
__global__ __launch_bounds__(512, 2)
void gemm_kernel(const uint16_t* __restrict__ A, const uint16_t* __restrict__ W,
                 const float* __restrict__ bias, void* __restrict__ outp,
                 const int* __restrict__ rowidx, const int* __restrict__ texp,
                 const int* __restrict__ tval, int K) {
  __shared__ uint16_t lds[8 * 8192];   // 8 half-slots x 16KB = 128KB

  const int tid = threadIdx.x;
  const int w = tid >> 6, l = tid & 63;

  // XCD-locality swizzle: grid = 8 xcd * mpx * 4 ntiles; mpx = gridDim.x/32
  const int lin = blockIdx.x;
  const int xcd = lin & 7;
  const int j   = lin >> 3;
  const int mpx = gridDim.x >> 5;
  const int my  = xcd * mpx + (j >> 2);
  const int nx  = j & 3;
  const int m0 = my * TM;
  const int n0 = nx * TM;

  int e = 0, valid = TM;
  if (REL) {
    e = texp[my];
    valid = tval[my];
    if (valid == 0) return;            // block-uniform, before any barrier
  }

  // ---- staging addresses: loadblock b=2w+j covers rows 16b..16b+15 of the half
  // lane l: row_local = 16b + (l>>2), phys chunk = l&3, c_log = (l&3)^((l>>2)&3)
  // (pre-swizzled source; LDS dest linear => layout c_phys = c_log ^ (row&3))
  const int rlo  = l >> 2;
  const int clog = (l & 3) ^ (rlo & 3);
  const uint16_t* pA[2]; const uint16_t* pB[2];
  const uint16_t* We = W + (size_t)e * N_DIM * K;
  #pragma unroll
  for (int jj = 0; jj < 2; jj++) {
    const int b  = 2 * w + jj;
    const int rr = 16 * b + rlo;       // 0..255
    int gr = m0 + rr;
    if (REL) gr = rowidx[gr];
    pA[jj] = A  + (size_t)gr * K + clog * 8;
    pB[jj] = We + (size_t)(n0 + rr) * K + clog * 8;
  }

  // ---- frag read bases (element offsets within a 16KB slot: row*32 + physchunk*8)
  const int wm = w >> 2, wn = w & 3;         // 2x4 waves, each 128x64 of C
  const int q16 = l >> 4, r16 = l & 15;
  const int phys = q16 ^ (r16 & 3);
  const int abase = (wm * 128 + r16) * 32 + phys * 8;
  const int bbase = (wn * 64  + r16) * 32 + phys * 8;

  f32x4 acc[8][4];
  #pragma unroll
  for (int i = 0; i < 8; i++)
    #pragma unroll
    for (int jj = 0; jj < 4; jj++) {
      f32x4 z = {0.f, 0.f, 0.f, 0.f};
      acc[i][jj] = z;
    }
  bf16x8 af[8], bf[2];

  auto STAGE = [&](int h) {                  // stage half h into slot h&7
    const int sl = (h & 7) * 8192;
    const int c  = h & 3;
    const int ko = (h >> 2) * 64 + (c >> 1) * 32;
    const uint16_t* g0 = (c & 1) ? pB[0] : pA[0];
    const uint16_t* g1 = (c & 1) ? pB[1] : pA[1];
    async_cp16(g0 + ko, &lds[sl + (2 * w + 0) * 512 + l * 8]);
    async_cp16(g1 + ko, &lds[sl + (2 * w + 1) * 512 + l * 8]);
  };

  const int NT = K >> 6;                     // K-tiles (8 for K=512, 16 for K=1024)

  // prologue: stage halves 0..5; wait oldest 4 (halves 0,1 = kh0 of tile 0)
  #pragma unroll
  for (int h = 0; h < 6; h++) STAGE(h);
  asm volatile("s_waitcnt vmcnt(8)" ::: "memory");
  __builtin_amdgcn_s_barrier();

  for (int T = 0; T < NT; ++T) {
    const int p0 = 4 * T;
    const int slA0 = ((p0    ) & 7) * 8192;
    const int slB0 = ((p0 + 1) & 7) * 8192;
    const int slA1 = ((p0 + 2) & 7) * 8192;
    const int slB1 = ((p0 + 3) & 7) * 8192;
    const bool s01 = (T <= NT - 2);
    const bool s23 = (T <= NT - 3);

    // ---- phase 0: C cols 0..31 (j01) x kh0
    LDA_FRAGS(slA0);
    LDB_FRAGS(slB0, 0);
    if (s01) STAGE(p0 + 6);
    __builtin_amdgcn_s_barrier();
    __builtin_amdgcn_s_setprio(1);
    MFMA_PAIR(0);
    __builtin_amdgcn_s_setprio(0);
    __builtin_amdgcn_s_barrier();

    // ---- phase 1: C cols 32..63 (j23) x kh0
    LDB_FRAGS(slB0, 1);
    if (s01) STAGE(p0 + 7);
    __builtin_amdgcn_s_barrier();
    __builtin_amdgcn_s_setprio(1);
    MFMA_PAIR(1);
    __builtin_amdgcn_s_setprio(0);
    if (T < NT - 1) { asm volatile("s_waitcnt vmcnt(8)" ::: "memory"); }
    else            { asm volatile("s_waitcnt vmcnt(0)" ::: "memory"); }
    __builtin_amdgcn_s_barrier();

    // ---- phase 2: j01 x kh1
    LDA_FRAGS(slA1);
    LDB_FRAGS(slB1, 0);
    if (s23) STAGE(p0 + 8);
    __builtin_amdgcn_s_barrier();
    __builtin_amdgcn_s_setprio(1);
    MFMA_PAIR(0);
    __builtin_amdgcn_s_setprio(0);
    __builtin_amdgcn_s_barrier();

    // ---- phase 3: j23 x kh1
    LDB_FRAGS(slB1, 1);
    if (s23) STAGE(p0 + 9);
    __builtin_amdgcn_s_barrier();
    __builtin_amdgcn_s_setprio(1);
    MFMA_PAIR(1);
    __builtin_amdgcn_s_setprio(0);
    if (T < NT - 2)       { asm volatile("s_waitcnt vmcnt(8)" ::: "memory"); }
    else if (T == NT - 2) { asm volatile("s_waitcnt vmcnt(4)" ::: "memory"); }
    __builtin_amdgcn_s_barrier();
  }

  // ---- epilogue: C/D layout col=lane&15, row=(lane>>4)*4+reg (verified)
  float bj[4];
  #pragma unroll
  for (int jj = 0; jj < 4; jj++)
    bj[jj] = bias[(size_t)e * N_DIM + n0 + wn * 64 + jj * 16 + r16];

  #pragma unroll
  for (int i = 0; i < 8; i++) {
    #pragma unroll
    for (int r = 0; r < 4; r++) {
      const int rl = wm * 128 + i * 16 + q16 * 4 + r;     // row within 256-tile
      if (REL && rl >= valid) continue;
      int orow = m0 + rl;
      if (REL) orow = rowidx[m0 + rl];
      if (F32OUT) {
        float* o = (float*)outp + (size_t)orow * N_DIM + n0 + wn * 64 + r16;
        #pragma unroll
        for (int jj = 0; jj < 4; jj++) {
          float v = acc[i][jj][r] + bj[jj];
          if (RELU) v = fmaxf(v, 0.f);
          o[jj * 16] = v;
        }
      } else {
        uint16_t* o = (uint16_t*)outp + (size_t)orow * N_DIM + n0 + wn * 64 + r16;
        #pragma unroll
        for (int jj = 0; jj < 4; jj++) {
          float v = acc[i][jj][r] + bj[jj];
          if (RELU) v = fmaxf(v, 0.f);
          o[jj * 16] = f2bf(v);
        }
      }
    }
  }
}

// ---------------- launch ----------------
extern "C" void kernel_launch(void* const* d_in, const int* in_sizes, int n_in,
                              void* d_out, int out_size, void* d_ws, size_t ws_size,
                              hipStream_t stream) {
  const float* x   = (const float*)d_in[0];
  const int*   rel = (const int*)d_in[1];
  const float* W0  = (const float*)d_in[2];
  const float* b0  = (const float*)d_in[3];
  const float* W1  = (const float*)d_in[4];
  const float* b1  = (const float*)d_in[5];
  const float* RW1 = (const float*)d_in[6];
  const float* Rb1 = (const float*)d_in[7];
  const float* RW2 = (const float*)d_in[8];
  const float* Rb2 = (const float*)d_in[9];
  const float* RW3 = (const float*)d_in[10];
  const float* Rb3 = (const float*)d_in[11];
  float* out = (float*)d_out;

  // workspace (bytes): xb 16MB @0 | wt 32MB @16MB | hA 32MB @48MB | hB 32MB @80MB | meta @112MB
  char* ws = (char*)d_ws;
  uint16_t* xb = (uint16_t*)(ws);
  uint16_t* wt = (uint16_t*)(ws + (size_t)(16u << 20));
  uint16_t* hA = (uint16_t*)(ws + (size_t)(48u << 20));
  uint16_t* hB = (uint16_t*)(ws + (size_t)(80u << 20));
  int* rowidx = (int*)(ws + (size_t)(112u << 20));
  int* texp   = rowidx + PADDED_ROWS;
  int* tval   = texp + MAX_TILES;

  const dim3 blk(256);
  const dim3 gblk(512);
  const dim3 gDense((B_ROWS / TM) * 4);            // 64 mtiles * 4 ntiles = 256
  const dim3 gRel(MAX_TILES * 4);                  // 80 * 4 = 320

  setup_kernel<<<dim3(1), dim3(1024), 0, stream>>>(rel, rowidx, texp, tval);
  conv_x_kernel<<<dim3((B_ROWS * D_IN) / 4 / 256), blk, 0, stream>>>(x, xb, (B_ROWS * D_IN) / 4);

  // L0: hA = relu(x @ W0 + b0), K=512, dense
  transpose_conv_kernel<<<dim3(N_DIM / 64, D_IN / 64, 1), blk, 0, stream>>>(W0, wt, D_IN, N_DIM);
  gemm_kernel<false, true, false><<<gDense, gblk, 0, stream>>>(
      xb, wt, b0, hA, nullptr, nullptr, nullptr, D_IN);

  // L1: hB = relu(hA @ W1 + b1), K=1024, dense
  transpose_conv_kernel<<<dim3(N_DIM / 64, N_DIM / 64, 1), blk, 0, stream>>>(W1, wt, N_DIM, N_DIM);
  gemm_kernel<false, true, false><<<gDense, gblk, 0, stream>>>(
      hA, wt, b1, hB, nullptr, nullptr, nullptr, N_DIM);

  // L2: hA[orig] = relu(gather(hB) @ RW1[r] + Rb1[r])  (gather+scatter via rowidx)
  transpose_conv_kernel<<<dim3(N_DIM / 64, N_DIM / 64, NREL), blk, 0, stream>>>(RW1, wt, N_DIM, N_DIM);
  gemm_kernel<true, true, false><<<gRel, gblk, 0, stream>>>(
      hB, wt, Rb1, hA, rowidx, texp, tval, N_DIM);

  // L3: hB[orig] = relu(gather(hA) @ RW2[r] + Rb2[r])
  transpose_conv_kernel<<<dim3(N_DIM / 64, N_DIM / 64, NREL), blk, 0, stream>>>(RW2, wt, N_DIM, N_DIM);
  gemm_kernel<true, true, false><<<gRel, gblk, 0, stream>>>(
      hA, wt, Rb2, hB, rowidx, texp, tval, N_DIM);

  // L4: out[orig] = gather(hB) @ RW3[r] + Rb3[r], fp32, no relu
  transpose_conv_kernel<<<dim3(N_DIM / 64, N_DIM / 64, NREL), blk, 0, stream>>>(RW3, wt, N_DIM, N_DIM);
  gemm_kernel<true, false, true><<<gRel, gblk, 0, stream>>>(
      hB, wt, Rb3, out, rowidx, texp, tval, N_DIM);

  (void)in_sizes; (void)n_in; (void)out_size; (void)ws_size;
}

// Round 3
// 520.977 us; speedup vs baseline: 1.1248x; 1.1248x over previous
//
#include <hip/hip_runtime.h>
#include <stdint.h>

// ---------------- problem constants ----------------
#define B_ROWS   16384
#define D_IN     512
#define N_DIM    1024
#define NREL     16
#define TM       128
#define TN       128
#define BK       32
#define MAX_TILES 144                 // <= B_ROWS/TM + NREL-1 padding tiles
#define PADDED_ROWS (MAX_TILES * TM)  // 18432

typedef __bf16 bf16x8 __attribute__((ext_vector_type(8)));
typedef float  f32x4  __attribute__((ext_vector_type(4)));

__device__ __forceinline__ uint16_t f2bf(float f) {
  union { float f; uint32_t u; } v; v.f = f;
  return (uint16_t)((v.u + 0x7fffu + ((v.u >> 16) & 1u)) >> 16);   // RNE
}

// async global->LDS 16B copy. LDS dest must be (wave-uniform base + lane*16).
__device__ __forceinline__ void async_cp16(const uint16_t* g, uint16_t* l) {
  __builtin_amdgcn_global_load_lds(
      (__attribute__((address_space(1))) void*)(g),
      (__attribute__((address_space(3))) void*)(l), 16, 0, 0);
}

// ---------------- setup: histogram relations, build padded permutation ----------------
__global__ void setup_kernel(const int* __restrict__ rel, int* __restrict__ rowidx,
                             int* __restrict__ texp, int* __restrict__ tval) {
  __shared__ int cnt[NREL], segstart[NREL], cursor[NREL];
  const int t = threadIdx.x;
  const int nt_ = blockDim.x;
  if (t < NREL) { cnt[t] = 0; cursor[t] = 0; }
  __syncthreads();
  for (int i = t; i < B_ROWS; i += nt_) atomicAdd(&cnt[rel[i]], 1);
  __syncthreads();
  if (t == 0) {
    int slot = 0, tile = 0;
    for (int r = 0; r < NREL; r++) {
      segstart[r] = slot;
      const int c = cnt[r];
      const int nt = (c + TM - 1) / TM;
      for (int k = 0; k < nt; k++) {
        texp[tile + k] = r;
        const int rem = c - k * TM;
        tval[tile + k] = rem < TM ? rem : TM;
      }
      tile += nt; slot += nt * TM;
    }
    for (; tile < MAX_TILES; tile++) { texp[tile] = 0; tval[tile] = 0; }
  }
  __syncthreads();
  for (int i = t; i < PADDED_ROWS; i += nt_) rowidx[i] = 0;  // padded slots -> row 0 (safe loads)
  __syncthreads();
  for (int i = t; i < B_ROWS; i += nt_) {
    const int r = rel[i];
    const int p = atomicAdd(&cursor[r], 1);
    rowidx[segstart[r] + p] = i;
  }
}

// ---------------- fp32 -> bf16 elementwise (x) ----------------
__global__ void conv_x_kernel(const float* __restrict__ in, uint16_t* __restrict__ out, int n4) {
  const int i = blockIdx.x * blockDim.x + threadIdx.x;
  if (i < n4) {
    const float4 v = ((const float4*)in)[i];
    uint2 o;
    o.x = (uint32_t)f2bf(v.x) | ((uint32_t)f2bf(v.y) << 16);
    o.y = (uint32_t)f2bf(v.z) | ((uint32_t)f2bf(v.w) << 16);
    ((uint2*)out)[i] = o;
  }
}

// ---------------- W[K][N] fp32 -> Wt[N][K] bf16, 64x64 tiles, vectorized ----------------
__global__ __launch_bounds__(256)
void transpose_conv_kernel(const float* __restrict__ W, uint16_t* __restrict__ Wt,
                           int K, int N) {
  // t32[n_local][k_pair]: packed pair (k even in low16, k odd in high16). stride 33 dodges conflicts.
  __shared__ uint32_t t32[64][33];
  const size_t mat = (size_t)K * N;
  const float*    Wp  = W  + mat * blockIdx.z;
  uint16_t*       Wtp = Wt + mat * blockIdx.z;
  const int n0 = blockIdx.x * 64, k0 = blockIdx.y * 64;
  const int tx = threadIdx.x & 15;     // n-quad
  const int ty = threadIdx.x >> 4;     // 0..15
  #pragma unroll
  for (int rb = 0; rb < 2; rb++) {
    const int kp = rb * 16 + ty;       // k-pair 0..31
    const int k  = k0 + kp * 2;
    const float4 r0 = *(const float4*)&Wp[(size_t)k * N + n0 + tx * 4];
    const float4 r1 = *(const float4*)&Wp[(size_t)(k + 1) * N + n0 + tx * 4];
    t32[tx * 4 + 0][kp] = (uint32_t)f2bf(r0.x) | ((uint32_t)f2bf(r1.x) << 16);
    t32[tx * 4 + 1][kp] = (uint32_t)f2bf(r0.y) | ((uint32_t)f2bf(r1.y) << 16);
    t32[tx * 4 + 2][kp] = (uint32_t)f2bf(r0.z) | ((uint32_t)f2bf(r1.z) << 16);
    t32[tx * 4 + 3][kp] = (uint32_t)f2bf(r0.w) | ((uint32_t)f2bf(r1.w) << 16);
  }
  __syncthreads();
  #pragma unroll
  for (int rb = 0; rb < 4; rb++) {
    const int nl = rb * 16 + ty;
    uint2 v; v.x = t32[nl][2 * tx]; v.y = t32[nl][2 * tx + 1];
    *(uint2*)&Wtp[(size_t)(n0 + nl) * K + k0 + tx * 4] = v;
  }
}

// ---------------- GEMM: C = [relu](A @ Wt^T + bias), 128x128xBK32 ----------------
// Main loop identical to the verified 517us kernel (XCD swizzle, LDS dbuf,
// counted vmcnt(4)). Epilogue changed: LDS-bounce -> 16B coalesced stores
// (8 VMEM store insts/thread instead of 64 scalar stores).
template<bool GATHER, bool EXPERT, bool RELU, bool SCATTER>
__global__ __launch_bounds__(256)
void gemm_kernel(const uint16_t* __restrict__ A, const uint16_t* __restrict__ W,
                 const float* __restrict__ bias, void* __restrict__ outp,
                 const int* __restrict__ rowidx, const int* __restrict__ texp,
                 const int* __restrict__ tval, int K) {
  __shared__ uint16_t smem[4 * TM * BK];   // 32KB: staging dbuf, reused by epilogue
  uint16_t (*sA)[TM * BK] = (uint16_t (*)[TM * BK])smem;
  uint16_t (*sB)[TN * BK] = (uint16_t (*)[TN * BK])(smem + 2 * TM * BK);

  const int tid = threadIdx.x;
  const int w = tid >> 6, l = tid & 63;

  // XCD-locality swizzle: gridDim.x = 8 * NT_M, NT_M % 8 == 0. Each XCD gets a
  // contiguous m-strip with all 8 n-tiles -> A rows + the expert's W stay in L2.
  const int lin = blockIdx.x;
  const int xcd = lin & 7;
  const int j   = lin >> 3;
  const int mpx = gridDim.x >> 6;          // NT_M / 8
  const int my  = xcd * mpx + (j >> 3);
  const int nx  = j & 7;
  const int m0 = my * TM;
  const int n0 = nx * TN;

  int e = 0, valid = TM;
  if (EXPERT) {
    e = texp[my];
    valid = tval[my];
    if (valid == 0) return;            // block-uniform: no barrier divergence
  }

  // staging: wave w fills 1KB LDS chunks; lane l -> row 16w+(l>>2), slot chunk l&3,
  // global chunk (l&3) ^ sel(row)  [XOR swizzle keeps ds_read_b128 conflict-free]
  const int row0   = 16 * w + (l >> 2);
  const int sel    = (row0 ^ (row0 >> 2)) & 3;       // same for row0+64
  const int koff   = ((l & 3) ^ sel) * 8;
  int ar0 = m0 + row0, ar1 = m0 + 64 + row0;
  if (GATHER) { ar0 = rowidx[ar0]; ar1 = rowidx[ar1]; }
  const uint16_t* srcA0 = A + (size_t)ar0 * K + koff;
  const uint16_t* srcA1 = A + (size_t)ar1 * K + koff;
  const uint16_t* Wb    = W + (size_t)e * N_DIM * K;
  const uint16_t* srcB0 = Wb + (size_t)(n0 + row0) * K + koff;
  const uint16_t* srcB1 = Wb + (size_t)(n0 + 64 + row0) * K + koff;
  uint16_t* ldsA0 = &sA[0][w * 512 + l * 8];
  uint16_t* ldsA1 = &sA[0][2048 + w * 512 + l * 8];
  uint16_t* ldsB0 = &sB[0][w * 512 + l * 8];
  uint16_t* ldsB1 = &sB[0][2048 + w * 512 + l * 8];

  const int wm = w >> 1, wn = w & 1;        // 2x2 waves, each 64x64
  const int q = l >> 4, r16 = l & 15;
  const int selr = (r16 ^ (r16 >> 2)) & 3;  // sel(row) for read rows (i,wm drop out mod 4)
  const int cq = (q ^ selr) * 8;

  f32x4 acc[4][4];
  #pragma unroll
  for (int i = 0; i < 4; i++)
    #pragma unroll
    for (int jj = 0; jj < 4; jj++) {
      f32x4 z = {0.f, 0.f, 0.f, 0.f};
      acc[i][jj] = z;
    }

  const int nIter = K / BK;

  // prologue: stage tile 0 into buffer 0
  async_cp16(srcA0, ldsA0);
  async_cp16(srcA1, ldsA1);
  async_cp16(srcB0, ldsB0);
  async_cp16(srcB1, ldsB1);

  for (int k = 0; k < nIter; k++) {
    const int cur = k & 1;
    if (k + 1 < nIter) {
      // prefetch tile k+1 into the other buffer (4096 elements = 8KB apart)
      const int koff2 = (k + 1) * BK;
      const int boff  = (cur ^ 1) * 4096;
      async_cp16(srcA0 + koff2, ldsA0 + boff);
      async_cp16(srcA1 + koff2, ldsA1 + boff);
      async_cp16(srcB0 + koff2, ldsB0 + boff);
      async_cp16(srcB1 + koff2, ldsB1 + boff);
      // wait only the oldest 4 (tile k); tile k+1 stays in flight across the barrier
      asm volatile("s_waitcnt vmcnt(4)" ::: "memory");
    } else {
      asm volatile("s_waitcnt vmcnt(0)" ::: "memory");
    }
    __builtin_amdgcn_s_barrier();      // tile k resident for all waves

    bf16x8 af[4], bf[4];
    #pragma unroll
    for (int i = 0; i < 4; i++) {
      af[i] = *(const bf16x8*)(&sA[cur][(wm * 64 + i * 16 + r16) * BK + cq]);
      bf[i] = *(const bf16x8*)(&sB[cur][(wn * 64 + i * 16 + r16) * BK + cq]);
    }
    #pragma unroll
    for (int i = 0; i < 4; i++)
      #pragma unroll
      for (int jj = 0; jj < 4; jj++)
        acc[i][jj] = __builtin_amdgcn_mfma_f32_16x16x32_bf16(af[i], bf[jj], acc[i][jj], 0, 0, 0);

    // reads of buf[cur] are consumed by the MFMAs above (lgkm drained by use);
    // this barrier protects buf[cur] from tile k+2's DMA issued next iteration.
    __builtin_amdgcn_s_barrier();
  }

  // ---------------- epilogue (LDS-bounce, wide stores) ----------------
  // C/D layout col=lane&15, row=(lane>>4)*4+reg (m89/m91-verified).
  float bj[4];
  #pragma unroll
  for (int jj = 0; jj < 4; jj++)
    bj[jj] = bias[(size_t)e * N_DIM + n0 + wn * 64 + jj * 16 + r16];

  if (!SCATTER) {
    // bf16 out, rows m0+rl in (possibly padded) linear layout, garbage rows ok.
    #pragma unroll
    for (int i = 0; i < 4; i++)
      #pragma unroll
      for (int r = 0; r < 4; r++) {
        const int rl = wm * 64 + i * 16 + q * 4 + r;
        #pragma unroll
        for (int jj = 0; jj < 4; jj++) {
          float v = acc[i][jj][r] + bj[jj];
          if (RELU) v = fmaxf(v, 0.f);
          smem[rl * 128 + wn * 64 + jj * 16 + r16] = f2bf(v);
        }
      }
    __syncthreads();
    // 128x128 bf16 = 32KB = 8 chunks of (256 thr x 16B); 16 lanes cover one row seg
    #pragma unroll
    for (int c = 0; c < 8; c++) {
      const int off16 = c * 2048 + tid * 8;        // u16 units
      const int row = off16 >> 7, col = off16 & 127;
      uint16_t* dst = (uint16_t*)outp + (size_t)(m0 + row) * N_DIM + n0 + col;
      *(uint4*)dst = *(const uint4*)&smem[off16];
    }
  } else {
    // f32 scatter via rowidx; two 64-row passes through the 32KB buffer.
    float* smemf = (float*)smem;
    #pragma unroll
    for (int h = 0; h < 2; h++) {
      if (h) __syncthreads();                       // pass-0 reads done before reuse
      #pragma unroll
      for (int ii = 0; ii < 2; ii++) {
        const int i = 2 * h + ii;
        #pragma unroll
        for (int r = 0; r < 4; r++) {
          const int lr = wm * 32 + ii * 16 + q * 4 + r;   // 0..63 within pass
          #pragma unroll
          for (int jj = 0; jj < 4; jj++) {
            float v = acc[i][jj][r] + bj[jj];
            if (RELU) v = fmaxf(v, 0.f);
            smemf[lr * 128 + wn * 64 + jj * 16 + r16] = v;
          }
        }
      }
      __syncthreads();
      // 64 rows x 512B = 32KB = 8 chunks of (256 thr x 16B)
      #pragma unroll
      for (int c = 0; c < 8; c++) {
        const int offB = c * 4096 + tid * 16;
        const int lr = offB >> 9, colf = (offB & 511) >> 2;
        const int wmr = lr >> 5, rem = lr & 31;
        const int rl = wmr * 64 + (2 * h + (rem >> 4)) * 16 + (rem & 15);
        if (rl < valid) {
          const int orow = rowidx[m0 + rl];
          float* dst = (float*)outp + (size_t)orow * N_DIM + n0 + colf;
          *(float4*)dst = *(const float4*)((const char*)smemf + offB);
        }
      }
    }
  }
}

// ---------------- launch ----------------
extern "C" void kernel_launch(void* const* d_in, const int* in_sizes, int n_in,
                              void* d_out, int out_size, void* d_ws, size_t ws_size,
                              hipStream_t stream) {
  const float* x   = (const float*)d_in[0];
  const int*   rel = (const int*)d_in[1];
  const float* W0  = (const float*)d_in[2];
  const float* b0  = (const float*)d_in[3];
  const float* W1  = (const float*)d_in[4];
  const float* b1  = (const float*)d_in[5];
  const float* RW1 = (const float*)d_in[6];
  const float* Rb1 = (const float*)d_in[7];
  const float* RW2 = (const float*)d_in[8];
  const float* Rb2 = (const float*)d_in[9];
  const float* RW3 = (const float*)d_in[10];
  const float* Rb3 = (const float*)d_in[11];
  float* out = (float*)d_out;

  // workspace layout (bytes): xb 16MB | wt 32MB | ha 36MB | hb 36MB | rowidx/meta
  char* ws = (char*)d_ws;
  uint16_t* xb = (uint16_t*)(ws);
  uint16_t* wt = (uint16_t*)(ws + (size_t)(16u << 20));
  uint16_t* ha = (uint16_t*)(ws + (size_t)(48u << 20));
  uint16_t* hb = (uint16_t*)(ws + (size_t)(84u << 20));
  int* rowidx = (int*)(ws + (size_t)(120u << 20));
  int* texp   = rowidx + PADDED_ROWS;
  int* tval   = texp + MAX_TILES;

  const dim3 blk(256);
  const dim3 gDense(8 * (B_ROWS / TM));           // 1D, XCD-swizzled in-kernel
  const dim3 gRel(8 * MAX_TILES);

  setup_kernel<<<dim3(1), dim3(1024), 0, stream>>>(rel, rowidx, texp, tval);
  conv_x_kernel<<<dim3((B_ROWS * D_IN) / 4 / 256), blk, 0, stream>>>(x, xb, (B_ROWS * D_IN) / 4);

  // L0: h = relu(x @ W0 + b0), K=512
  transpose_conv_kernel<<<dim3(N_DIM / 64, D_IN / 64, 1), blk, 0, stream>>>(W0, wt, D_IN, N_DIM);
  gemm_kernel<false, false, true, false><<<gDense, blk, 0, stream>>>(
      xb, wt, b0, ha, nullptr, nullptr, nullptr, D_IN);

  // L1: h = relu(h @ W1 + b1), K=1024
  transpose_conv_kernel<<<dim3(N_DIM / 64, N_DIM / 64, 1), blk, 0, stream>>>(W1, wt, N_DIM, N_DIM);
  gemm_kernel<false, false, true, false><<<gDense, blk, 0, stream>>>(
      ha, wt, b1, hb, nullptr, nullptr, nullptr, N_DIM);

  // L2: gather rows by relation, relu(h @ RW1[r] + Rb1[r]) -> padded layout
  transpose_conv_kernel<<<dim3(N_DIM / 64, N_DIM / 64, NREL), blk, 0, stream>>>(RW1, wt, N_DIM, N_DIM);
  gemm_kernel<true, true, true, false><<<gRel, blk, 0, stream>>>(
      hb, wt, Rb1, ha, rowidx, texp, tval, N_DIM);

  // L3: relu(h @ RW2[r] + Rb2[r]) in padded layout
  transpose_conv_kernel<<<dim3(N_DIM / 64, N_DIM / 64, NREL), blk, 0, stream>>>(RW2, wt, N_DIM, N_DIM);
  gemm_kernel<false, true, true, false><<<gRel, blk, 0, stream>>>(
      ha, wt, Rb2, hb, rowidx, texp, tval, N_DIM);

  // L4: out[orig_row] = h @ RW3[r] + Rb3[r], fp32 scatter, no relu
  transpose_conv_kernel<<<dim3(N_DIM / 64, N_DIM / 64, NREL), blk, 0, stream>>>(RW3, wt, N_DIM, N_DIM);
  gemm_kernel<false, true, false, true><<<gRel, blk, 0, stream>>>(
      hb, wt, Rb3, out, rowidx, texp, tval, N_DIM);

  (void)in_sizes; (void)n_in; (void)out_size; (void)ws_size;
}